// Round 7
// baseline (408.423 us; speedup 1.0000x reference)
//
#include <hip/hip_runtime.h>

typedef _Float16 f16;
typedef _Float16 f16x8 __attribute__((ext_vector_type(8)));
typedef _Float16 f16x4 __attribute__((ext_vector_type(4)));
typedef float f32x4 __attribute__((ext_vector_type(4)));
typedef float f32x16 __attribute__((ext_vector_type(16)));

constexpr int NB = 32, NS = 576, ND = 768, NG = 24;
constexpr int M_TOT = NB * NS;   // 18432
constexpr int N_TOT = 3 * ND;    // 2304

// ---------------- kernel 1: fused prep = {W transpose-cast} + {WcT hi/lo + bc} + {x->f16 cast}
// blocks 0..431: WT transpose-cast; 432..1200: WcT/bc; 1201..2352: xb = (f16)x (16 rows each).
__global__ __launch_bounds__(256) void prep_kernel(const float* __restrict__ x,
                                                   const float* __restrict__ Wq,
                                                   const float* __restrict__ Wk,
                                                   const float* __restrict__ Wv,
                                                   const float* __restrict__ bq,
                                                   const float* __restrict__ bk,
                                                   const float* __restrict__ W1,
                                                   const float* __restrict__ b1,
                                                   f16* __restrict__ WT,
                                                   f16* __restrict__ WcT_hi,
                                                   f16* __restrict__ WcT_lo,
                                                   float* __restrict__ bc,
                                                   f16* __restrict__ xb) {
  __shared__ __align__(16) float smem[64 * 65];
  if (blockIdx.x >= 1201) {
    // ---- x cast part: block c covers 16 rows = 12288 elements ----
    size_t base = (size_t)(blockIdx.x - 1201) * 12288;
    const float* xs = x + base;
    f16* xd = xb + base;
#pragma unroll
    for (int it = 0; it < 6; ++it) {
      int e = threadIdx.x * 8 + it * 2048;
      float4 u0 = *(const float4*)(xs + e);
      float4 u1 = *(const float4*)(xs + e + 4);
      f16x8 h;
      h[0] = (f16)u0.x; h[1] = (f16)u0.y; h[2] = (f16)u0.z; h[3] = (f16)u0.w;
      h[4] = (f16)u1.x; h[5] = (f16)u1.y; h[6] = (f16)u1.z; h[7] = (f16)u1.w;
      *(f16x8*)(xd + e) = h;
    }
    return;
  }
  if (blockIdx.x < 432) {
    float (*tile)[65] = (float(*)[65])smem;
    int bt = blockIdx.x;                 // 0..431
    int ntile = bt / 12, ktile = bt % 12;
    const float* src = (ntile < 12) ? Wq : ((ntile < 24) ? Wk : Wv);
    int n0 = (ntile % 12) * 64, k0 = ktile * 64;
    int cc = threadIdx.x & 63, rr = threadIdx.x >> 6;
#pragma unroll
    for (int i = 0; i < 16; i++) {
      int k = rr + i * 4;
      tile[cc][k] = src[(size_t)(k0 + k) * ND + n0 + cc];
    }
    __syncthreads();
#pragma unroll
    for (int i = 0; i < 16; i++) {
      int n = rr + i * 4;
      WT[(size_t)(ntile * 64 + n) * ND + k0 + cc] = (f16)tile[n][cc];
    }
    return;
  }
  // ---- wcT part ----
  float (*part)[64] = (float(*)[64])smem;
  int blk = blockIdx.x - 432;               // 0..768
  int wave = threadIdx.x >> 6, lane = threadIdx.x & 63;
  int c = (lane < 60) ? lane : 59;
  int j0 = wave * 192;
  if (blk == 768) {
    float acc = 0.f;
    for (int j = j0; j < j0 + 192; j++)
      acc += bq[j] * W1[j * 60 + c] + bk[j] * W1[(ND + j) * 60 + c];
    part[wave][lane] = acc;
    __syncthreads();
    if (wave == 0 && lane < 60)
      bc[lane] = b1[lane] + part[0][lane] + part[1][lane] + part[2][lane] + part[3][lane];
    return;
  }
  int r = blk;                              // 0..767
  const float* wq = Wq + (size_t)r * ND;
  const float* wk = Wk + (size_t)r * ND;
  float acc = 0.f;
  for (int j = j0; j < j0 + 192; j++)
    acc += wq[j] * W1[j * 60 + c] + wk[j] * W1[(ND + j) * 60 + c];
  part[wave][lane] = acc;
  __syncthreads();
  if (wave == 0 && lane < 60) {
    float v = part[0][lane] + part[1][lane] + part[2][lane] + part[3][lane];
    f16 hi = (f16)v;
    WcT_hi[(size_t)lane * ND + r] = hi;
    WcT_lo[(size_t)lane * ND + r] = (f16)(v - (float)hi);
  }
}

// ---------------- kernel 2: MERGED z1 + gemm ------------------------------------------------
// z1 and gemm are data-independent (gemm reads xb from prep; z1 produces only coords).
// blocks [0,1152): z1 path (r6 body minus the xb store). blocks [1152,3744): gemm path,
// r3-verbatim 128x128 multi-block structure (proven 102.8-103.6 us across rounds 0/3).
// Merging co-schedules z1's latency-bound blocks with gemm's MFMA blocks on the same CUs ->
// z1's wall time hides under gemm instead of serializing after it. WcT_hi/lo relocated out
// of the qkv alias region (gemm writes qkv concurrently with z1 reading WcT).
__device__ __forceinline__ void async_copy16(const f16* g, f16* l) {
  __builtin_amdgcn_global_load_lds((const __attribute__((address_space(1))) void*)g,
                                   (__attribute__((address_space(3))) void*)l, 16, 0, 0);
}

__global__ __launch_bounds__(256) void z1gemm_kernel(const float* __restrict__ x,
                                                     const f16* __restrict__ xbA,   // A (f16 x)
                                                     const f16* __restrict__ Bt,    // WT
                                                     const f16* __restrict__ WcT_hi,
                                                     const f16* __restrict__ WcT_lo,
                                                     const float* __restrict__ bc,
                                                     const float* __restrict__ W2,
                                                     const float* __restrict__ b2,
                                                     const float* __restrict__ W3,
                                                     const float* __restrict__ b3,
                                                     const float* __restrict__ bq,
                                                     const float* __restrict__ bk,
                                                     const float* __restrict__ bv,
                                                     f16* __restrict__ C,           // qkv
                                                     float* __restrict__ coords) {
  __shared__ __align__(16) char smem[32768];
  if (blockIdx.x < 1152) {
    // =================== z1 path ===================
    float (*red)[16][64] = (float(*)[16][64])smem;           // [3][16][64] = 12 KB
    float (*htile)[60]   = (float(*)[60])(smem + 12288);     // 16x60 = 3.75 KB
    int wave = threadIdx.x >> 6, lane = threadIdx.x & 63;
    int q = lane >> 4, r16 = lane & 15;
    int m0 = blockIdx.x * 16;
    int k0 = wave * 192;
    const float* xr = x + (size_t)(m0 + r16) * ND + k0;

    f32x4 acc[4];
#pragma unroll
    for (int nf = 0; nf < 4; nf++) acc[nf] = 0.f;

    for (int kk = 0; kk < 192; kk += 32) {
      int ko = kk + q * 8;
      float4 v0 = *(const float4*)(xr + ko);
      float4 v1 = *(const float4*)(xr + ko + 4);
      f16x8 a_hi, a_lo;
      float xv[8] = {v0.x, v0.y, v0.z, v0.w, v1.x, v1.y, v1.z, v1.w};
#pragma unroll
      for (int j = 0; j < 8; j++) {
        f16 h = (f16)xv[j];
        a_hi[j] = h;
        a_lo[j] = (f16)(xv[j] - (float)h);
      }
      f16x8 b_hi[4], b_lo[4];
#pragma unroll
      for (int nf = 0; nf < 4; nf++) {
        size_t off = (size_t)(nf * 16 + r16) * ND + k0 + ko;
        b_hi[nf] = *(const f16x8*)(WcT_hi + off);
        b_lo[nf] = *(const f16x8*)(WcT_lo + off);
      }
#pragma unroll
      for (int nf = 0; nf < 4; nf++) {
        acc[nf] = __builtin_amdgcn_mfma_f32_16x16x32_f16(a_hi, b_hi[nf], acc[nf], 0, 0, 0);
        acc[nf] = __builtin_amdgcn_mfma_f32_16x16x32_f16(a_lo, b_hi[nf], acc[nf], 0, 0, 0);
        acc[nf] = __builtin_amdgcn_mfma_f32_16x16x32_f16(a_hi, b_lo[nf], acc[nf], 0, 0, 0);
      }
    }

    if (wave > 0) {
#pragma unroll
      for (int nf = 0; nf < 4; nf++)
#pragma unroll
        for (int r = 0; r < 4; r++) red[wave - 1][nf * 4 + r][lane] = acc[nf][r];
    }
    __syncthreads();
    if (wave == 0) {
#pragma unroll
      for (int nf = 0; nf < 4; nf++) {
        int col = nf * 16 + r16;
        if (col < 60) {
          float bcv = bc[col];
#pragma unroll
          for (int r = 0; r < 4; r++) {
            float v = acc[nf][r] + red[0][nf * 4 + r][lane] + red[1][nf * 4 + r][lane]
                    + red[2][nf * 4 + r][lane] + bcv;
            htile[q * 4 + r][col] = fmaxf(v, 0.f);
          }
        }
      }
    }
    __syncthreads();

    int c = (lane < 60) ? lane : 59;
    float b2v = b2[c];
    float w30 = W3[c * 2 + 0], w31 = W3[c * 2 + 1];
#pragma unroll
    for (int rr = 0; rr < 4; rr++) {
      int row = wave * 4 + rr;
      float acc2 = b2v;
      for (int j = 0; j < 60; j++) acc2 = fmaf(htile[row][j], W2[j * 60 + c], acc2);
      float h2 = fmaxf(acc2, 0.f);
      float p0 = (lane < 60) ? h2 * w30 : 0.f;
      float p1 = (lane < 60) ? h2 * w31 : 0.f;
#pragma unroll
      for (int o = 32; o > 0; o >>= 1) { p0 += __shfl_down(p0, o); p1 += __shfl_down(p1, o); }
      if (lane == 0) {
        float s0 = tanhf(p0 + b3[0]);
        float s1 = tanhf(p1 + b3[1]);
        int m = m0 + row;
        int b = m / NS, s = m % NS;
        float* cb = coords + (size_t)b * (2 * NS);
        cb[(s >> 1) * 2 + (s & 1)] = s0;
        cb[(288 + (s >> 1)) * 2 + (s & 1)] = s1;
      }
    }
    return;
  }

  // =================== gemm path (r3-verbatim) ===================
  constexpr int BM = 128, BK = 64;
  f16* sA = (f16*)smem;                       // 16 KB
  f16* sB = (f16*)(smem + 16384);             // 16 KB

  // XCD-bijective remap: 2592 = 8*324 (offset 1152 is %8==0 -> XCD id preserved).
  int orig = blockIdx.x - 1152;
  int wg = (orig & 7) * 324 + (orig >> 3);
  int bm = wg / 18, bn = wg % 18;
  int tid = threadIdx.x;
  int wave = tid >> 6, lane = tid & 63;
  int wm = (wave >> 1) * 64, wn = (wave & 1) * 64;
  int m0 = bm * BM, n0 = bn * BM;

  int srow = tid >> 3;                          // 0..31
  int gchunk = ((tid & 7) ^ (srow & 7) ^ (((srow >> 3) & 3) << 1)) * 8;

  f32x16 acc[2][2];
#pragma unroll
  for (int i = 0; i < 2; i++)
#pragma unroll
    for (int j = 0; j < 2; j++) acc[i][j] = 0.f;

  int r32 = lane & 31, q2 = lane >> 5;
  int fx = (r32 & 7) ^ (((r32 >> 3) & 3) << 1);

  for (int kk = 0; kk < ND; kk += BK) {
#pragma unroll
    for (int ps = 0; ps < 4; ps++) {
      async_copy16(xbA + (size_t)(m0 + ps * 32 + srow) * ND + kk + gchunk, sA + ps * 2048 + tid * 8);
      async_copy16(Bt + (size_t)(n0 + ps * 32 + srow) * ND + kk + gchunk, sB + ps * 2048 + tid * 8);
    }
    __syncthreads();

#pragma unroll
    for (int ks = 0; ks < 4; ks++) {
      f16x8 aF[2], bF[2];
#pragma unroll
      for (int mt = 0; mt < 2; mt++) {
        int R = wm + mt * 32 + r32;
        aF[mt] = *(const f16x8*)(sA + R * 64 + (((ks * 2 + q2) ^ fx) * 8));
      }
#pragma unroll
      for (int nt = 0; nt < 2; nt++) {
        int R = wn + nt * 32 + r32;
        bF[nt] = *(const f16x8*)(sB + R * 64 + (((ks * 2 + q2) ^ fx) * 8));
      }
#pragma unroll
      for (int mt = 0; mt < 2; mt++)
#pragma unroll
        for (int nt = 0; nt < 2; nt++)   // swapped operands -> C^T register layout
          acc[mt][nt] = __builtin_amdgcn_mfma_f32_32x32x16_f16(bF[nt], aF[mt], acc[mt][nt], 0, 0, 0);
    }
    __syncthreads();
  }

#pragma unroll
  for (int mt = 0; mt < 2; mt++) {
    int gm = m0 + wm + mt * 32 + r32;
#pragma unroll
    for (int nt = 0; nt < 2; nt++) {
#pragma unroll
      for (int g = 0; g < 4; g++) {
        int gn0 = n0 + wn + nt * 32 + 8 * g + 4 * q2;
        const float* bp = (gn0 < ND) ? (bq + gn0)
                        : ((gn0 < 2 * ND) ? (bk + gn0 - ND) : (bv + gn0 - 2 * ND));
        float4 bias = *(const float4*)bp;
        f16x4 o;
        o[0] = (f16)(acc[mt][nt][4 * g + 0] + bias.x);
        o[1] = (f16)(acc[mt][nt][4 * g + 1] + bias.y);
        o[2] = (f16)(acc[mt][nt][4 * g + 2] + bias.z);
        o[3] = (f16)(acc[mt][nt][4 * g + 3] + bias.w);
        *(f16x4*)(C + (size_t)gm * N_TOT + gn0) = o;
      }
    }
  }
}

// ---------------- kernel 3: bilinear sample + score + sigmoid*value; XCD-swizzled ------------
__global__ __launch_bounds__(256) void sample_kernel(const f16* __restrict__ qkv,
                                                     const float* __restrict__ coords,
                                                     float* __restrict__ out) {
  int wave = threadIdx.x >> 6, t = threadIdx.x & 63;
  int x8 = blockIdx.x & 7;           // XCD heuristic (blockIdx % 8)
  int i = blockIdx.x >> 3;           // 0..575
  int b = x8 * 4 + (i / 144);        // batch
  int p = (i % 144) * 4 + wave;      // point in batch

  float gx = coords[(size_t)b * (2 * NS) + p * 2 + 0];
  float gy = coords[(size_t)b * (2 * NS) + p * 2 + 1];
  float ix = ((gx + 1.f) * (float)NG - 1.f) * 0.5f;
  float iy = ((gy + 1.f) * (float)NG - 1.f) * 0.5f;
  float x0f = floorf(ix), y0f = floorf(iy);
  float wx1 = ix - x0f, wx0 = 1.f - wx1;
  float wy1 = iy - y0f, wy0 = 1.f - wy1;
  int x0 = (int)x0f, y0 = (int)y0f, x1 = x0 + 1, y1 = y0 + 1;
  bool vx0 = (x0 >= 0) & (x0 <= NG - 1), vx1 = (x1 >= 0) & (x1 <= NG - 1);
  bool vy0 = (y0 >= 0) & (y0 <= NG - 1), vy1 = (y1 >= 0) & (y1 <= NG - 1);
  int cx0 = min(max(x0, 0), NG - 1), cx1 = min(max(x1, 0), NG - 1);
  int cy0 = min(max(y0, 0), NG - 1), cy1 = min(max(y1, 0), NG - 1);
  float w00 = wx0 * wy0 * ((vx0 && vy0) ? 1.f : 0.f);
  float w10 = wx1 * wy0 * ((vx1 && vy0) ? 1.f : 0.f);
  float w01 = wx0 * wy1 * ((vx0 && vy1) ? 1.f : 0.f);
  float w11 = wx1 * wy1 * ((vx1 && vy1) ? 1.f : 0.f);

  size_t base = (size_t)b * NS;
  const f16* r00 = qkv + (base + cy0 * NG + cx0) * N_TOT;
  const f16* r10 = qkv + (base + cy0 * NG + cx1) * N_TOT;
  const f16* r01 = qkv + (base + cy1 * NG + cx0) * N_TOT;
  const f16* r11 = qkv + (base + cy1 * NG + cx1) * N_TOT;
  const f16* qr  = qkv + (base + p) * N_TOT;

  float partial = 0.f;
  float outv[12];
#pragma unroll
  for (int ch = 0; ch < 3; ch++) {
    int d = ch * 256 + t * 4;        // coalesced: wave covers 256 contiguous channels
    f16x4 k00 = *(const f16x4*)(r00 + ND + d);
    f16x4 k10 = *(const f16x4*)(r10 + ND + d);
    f16x4 k01 = *(const f16x4*)(r01 + ND + d);
    f16x4 k11 = *(const f16x4*)(r11 + ND + d);
    f16x4 v00 = *(const f16x4*)(r00 + 2 * ND + d);
    f16x4 v10 = *(const f16x4*)(r10 + 2 * ND + d);
    f16x4 v01 = *(const f16x4*)(r01 + 2 * ND + d);
    f16x4 v11 = *(const f16x4*)(r11 + 2 * ND + d);
    f16x4 qv  = *(const f16x4*)(qr + d);
#pragma unroll
    for (int j = 0; j < 4; j++) {
      float sk = w00 * (float)k00[j] + w10 * (float)k10[j]
               + w01 * (float)k01[j] + w11 * (float)k11[j];
      float sv = w00 * (float)v00[j] + w10 * (float)v10[j]
               + w01 * (float)v01[j] + w11 * (float)v11[j];
      partial = fmaf((float)qv[j], sk, partial);
      outv[ch * 4 + j] = sv;
    }
  }
#pragma unroll
  for (int o = 32; o > 0; o >>= 1) partial += __shfl_down(partial, o);
  float score = __shfl(partial, 0);
  float sig = 1.f / (1.f + expf(-0.01f * score));
  float* orow = out + (size_t)(base + p) * ND;
#pragma unroll
  for (int ch = 0; ch < 3; ch++) {
    int d = ch * 256 + t * 4;
    float4 st;
    st.x = sig * outv[ch * 4 + 0]; st.y = sig * outv[ch * 4 + 1];
    st.z = sig * outv[ch * 4 + 2]; st.w = sig * outv[ch * 4 + 3];
    *(float4*)(orow + d) = st;
  }
}

extern "C" void kernel_launch(void* const* d_in, const int* in_sizes, int n_in,
                              void* d_out, int out_size, void* d_ws, size_t ws_size,
                              hipStream_t stream) {
  const float* x  = (const float*)d_in[0];
  const float* Wq = (const float*)d_in[2];
  const float* bq = (const float*)d_in[3];
  const float* Wk = (const float*)d_in[4];
  const float* bk = (const float*)d_in[5];
  const float* Wv = (const float*)d_in[6];
  const float* bv = (const float*)d_in[7];
  const float* W1 = (const float*)d_in[8];
  const float* b1 = (const float*)d_in[9];
  const float* W2 = (const float*)d_in[10];
  const float* b2 = (const float*)d_in[11];
  const float* W3 = (const float*)d_in[12];
  const float* b3 = (const float*)d_in[13];
  float* out = (float*)d_out;

  char* ws = (char*)d_ws;
  f16*   xb     = (f16*)(ws);                       // 28,311,552
  f16*   WT     = (f16*)(ws + 28311552);            //  3,538,944
  f16*   qkv    = (f16*)(ws + 31850496);            // 84,934,656 (ends 116,785,152)
  float* bc     = (float*)(ws + 116969472);         //        256
  // WcT moved OUT of the qkv alias region: z1 reads it concurrently with gemm writing qkv.
  f16*   WcT_hi = (f16*)(ws + 117000192);           //     98,304
  f16*   WcT_lo = (f16*)(ws + 117098496);           //     98,304 (ends 117,196,800)
  float* coords = (float*)(ws + 121393408);         //    147,456 (total 121,540,864)

  prep_kernel<<<dim3(432 + 769 + 1152), dim3(256), 0, stream>>>(x, Wq, Wk, Wv, bq, bk, W1, b1,
                                                                WT, WcT_hi, WcT_lo, bc, xb);
  z1gemm_kernel<<<dim3(1152 + (M_TOT / 128) * (N_TOT / 128)), dim3(256), 0, stream>>>(
      x, xb, WT, WcT_hi, WcT_lo, bc, W2, b2, W3, b3, bq, bk, bv, qkv, coords);
  sample_kernel<<<dim3(M_TOT / 4), dim3(256), 0, stream>>>(qkv, coords, out);
  (void)in_sizes; (void)n_in; (void)out_size; (void)ws_size;
}

// Round 8
// 332.750 us; speedup vs baseline: 1.2274x; 1.2274x over previous
//
#include <hip/hip_runtime.h>

typedef _Float16 f16;
typedef _Float16 f16x8 __attribute__((ext_vector_type(8)));
typedef _Float16 f16x4 __attribute__((ext_vector_type(4)));
typedef float f32x4 __attribute__((ext_vector_type(4)));
typedef float f32x16 __attribute__((ext_vector_type(16)));

constexpr int NB = 32, NS = 576, ND = 768, NG = 24;
constexpr int M_TOT = NB * NS;   // 18432
constexpr int N_TOT = 3 * ND;    // 2304

// ---------------- kernel 1: fused prep = {W transpose-cast} + {WcT hi/lo + bc} ---------------
// blocks 0..431: WT transpose-cast; 432..1200: WcT/bc. (The r7 x-cast branch is reverted:
// the cast stays fused in z1, which reads x once and writes xb as a side product.)
__global__ __launch_bounds__(256) void prep_kernel(const float* __restrict__ Wq,
                                                   const float* __restrict__ Wk,
                                                   const float* __restrict__ Wv,
                                                   const float* __restrict__ bq,
                                                   const float* __restrict__ bk,
                                                   const float* __restrict__ W1,
                                                   const float* __restrict__ b1,
                                                   f16* __restrict__ WT,
                                                   f16* __restrict__ WcT_hi,
                                                   f16* __restrict__ WcT_lo,
                                                   float* __restrict__ bc) {
  __shared__ __align__(16) float smem[64 * 65];
  if (blockIdx.x < 432) {
    float (*tile)[65] = (float(*)[65])smem;
    int bt = blockIdx.x;                 // 0..431
    int ntile = bt / 12, ktile = bt % 12;
    const float* src = (ntile < 12) ? Wq : ((ntile < 24) ? Wk : Wv);
    int n0 = (ntile % 12) * 64, k0 = ktile * 64;
    int cc = threadIdx.x & 63, rr = threadIdx.x >> 6;
#pragma unroll
    for (int i = 0; i < 16; i++) {
      int k = rr + i * 4;
      tile[cc][k] = src[(size_t)(k0 + k) * ND + n0 + cc];
    }
    __syncthreads();
#pragma unroll
    for (int i = 0; i < 16; i++) {
      int n = rr + i * 4;
      WT[(size_t)(ntile * 64 + n) * ND + k0 + cc] = (f16)tile[n][cc];
    }
    return;
  }
  // ---- wcT part ----
  float (*part)[64] = (float(*)[64])smem;
  int blk = blockIdx.x - 432;               // 0..768
  int wave = threadIdx.x >> 6, lane = threadIdx.x & 63;
  int c = (lane < 60) ? lane : 59;
  int j0 = wave * 192;
  if (blk == 768) {
    float acc = 0.f;
    for (int j = j0; j < j0 + 192; j++)
      acc += bq[j] * W1[j * 60 + c] + bk[j] * W1[(ND + j) * 60 + c];
    part[wave][lane] = acc;
    __syncthreads();
    if (wave == 0 && lane < 60)
      bc[lane] = b1[lane] + part[0][lane] + part[1][lane] + part[2][lane] + part[3][lane];
    return;
  }
  int r = blk;                              // 0..767
  const float* wq = Wq + (size_t)r * ND;
  const float* wk = Wk + (size_t)r * ND;
  float acc = 0.f;
  for (int j = j0; j < j0 + 192; j++)
    acc += wq[j] * W1[j * 60 + c] + wk[j] * W1[(ND + j) * 60 + c];
  part[wave][lane] = acc;
  __syncthreads();
  if (wave == 0 && lane < 60) {
    float v = part[0][lane] + part[1][lane] + part[2][lane] + part[3][lane];
    f16 hi = (f16)v;
    WcT_hi[(size_t)lane * ND + r] = hi;
    WcT_lo[(size_t)lane * ND + r] = (f16)(v - (float)hi);
  }
}

// ---------------- kernel 2: fused z1 MFMA + x cast + MLP tail + coord scatter (r3-verbatim) --
__global__ __launch_bounds__(256) void z1_fused_kernel(const float* __restrict__ x,
                                                       const f16* __restrict__ WcT_hi,
                                                       const f16* __restrict__ WcT_lo,
                                                       const float* __restrict__ bc,
                                                       const float* __restrict__ W2,
                                                       const float* __restrict__ b2,
                                                       const float* __restrict__ W3,
                                                       const float* __restrict__ b3,
                                                       f16* __restrict__ xb,
                                                       float* __restrict__ coords) {
  __shared__ float red[3][16][64];   // [wave-1][reg-idx][lane]
  __shared__ float htile[16][60];    // relu(z1) tile for this block's 16 rows
  int wave = threadIdx.x >> 6, lane = threadIdx.x & 63;
  int q = lane >> 4, r16 = lane & 15;
  int m0 = blockIdx.x * 16;
  int k0 = wave * 192;
  const float* xr = x + (size_t)(m0 + r16) * ND + k0;
  f16* xbr = xb + (size_t)(m0 + r16) * ND + k0;

  f32x4 acc[4];
#pragma unroll
  for (int nf = 0; nf < 4; nf++) acc[nf] = 0.f;

  for (int kk = 0; kk < 192; kk += 32) {
    int ko = kk + q * 8;
    float4 v0 = *(const float4*)(xr + ko);
    float4 v1 = *(const float4*)(xr + ko + 4);
    f16x8 a_hi, a_lo;
    float xv[8] = {v0.x, v0.y, v0.z, v0.w, v1.x, v1.y, v1.z, v1.w};
#pragma unroll
    for (int j = 0; j < 8; j++) {
      f16 h = (f16)xv[j];
      a_hi[j] = h;
      a_lo[j] = (f16)(xv[j] - (float)h);
    }
    *(f16x8*)(xbr + ko) = a_hi;      // fused fp32->f16 cast of x
    f16x8 b_hi[4], b_lo[4];
#pragma unroll
    for (int nf = 0; nf < 4; nf++) {
      size_t off = (size_t)(nf * 16 + r16) * ND + k0 + ko;
      b_hi[nf] = *(const f16x8*)(WcT_hi + off);
      b_lo[nf] = *(const f16x8*)(WcT_lo + off);
    }
#pragma unroll
    for (int nf = 0; nf < 4; nf++) {
      acc[nf] = __builtin_amdgcn_mfma_f32_16x16x32_f16(a_hi, b_hi[nf], acc[nf], 0, 0, 0);
      acc[nf] = __builtin_amdgcn_mfma_f32_16x16x32_f16(a_lo, b_hi[nf], acc[nf], 0, 0, 0);
      acc[nf] = __builtin_amdgcn_mfma_f32_16x16x32_f16(a_hi, b_lo[nf], acc[nf], 0, 0, 0);
    }
  }

  if (wave > 0) {
#pragma unroll
    for (int nf = 0; nf < 4; nf++)
#pragma unroll
      for (int r = 0; r < 4; r++) red[wave - 1][nf * 4 + r][lane] = acc[nf][r];
  }
  __syncthreads();
  if (wave == 0) {
#pragma unroll
    for (int nf = 0; nf < 4; nf++) {
      int col = nf * 16 + r16;
      if (col < 60) {
        float bcv = bc[col];
#pragma unroll
        for (int r = 0; r < 4; r++) {
          float v = acc[nf][r] + red[0][nf * 4 + r][lane] + red[1][nf * 4 + r][lane]
                  + red[2][nf * 4 + r][lane] + bcv;
          htile[q * 4 + r][col] = fmaxf(v, 0.f);
        }
      }
    }
  }
  __syncthreads();

  // MLP tail: wave w -> rows 4w..4w+3; lane c<60 owns layer-2 column c.
  int c = (lane < 60) ? lane : 59;
  float b2v = b2[c];
  float w30 = W3[c * 2 + 0], w31 = W3[c * 2 + 1];
#pragma unroll
  for (int rr = 0; rr < 4; rr++) {
    int row = wave * 4 + rr;
    float acc2 = b2v;
    for (int j = 0; j < 60; j++) acc2 = fmaf(htile[row][j], W2[j * 60 + c], acc2);
    float h2 = fmaxf(acc2, 0.f);
    float p0 = (lane < 60) ? h2 * w30 : 0.f;
    float p1 = (lane < 60) ? h2 * w31 : 0.f;
#pragma unroll
    for (int o = 32; o > 0; o >>= 1) { p0 += __shfl_down(p0, o); p1 += __shfl_down(p1, o); }
    if (lane == 0) {
      float s0 = tanhf(p0 + b3[0]);
      float s1 = tanhf(p1 + b3[1]);
      int m = m0 + row;
      int b = m / NS, s = m % NS;
      float* cb = coords + (size_t)b * (2 * NS);
      cb[(s >> 1) * 2 + (s & 1)] = s0;
      cb[(288 + (s >> 1)) * 2 + (s & 1)] = s1;
    }
  }
}

// ---------------- kernel 3: GEMM qkv = x_f16 @ [Wq|Wk|Wv]_f16 (r3-verbatim, 103 us) ---------
// 128x128 tile, BK=64, 32 KB LDS -> multi-block co-residency hides barrier drains (the proven
// mechanism on this 12-K-tile shape; 7 structural variants bracketed 102-116 us, this is best).
__device__ __forceinline__ void async_copy16(const f16* g, f16* l) {
  __builtin_amdgcn_global_load_lds((const __attribute__((address_space(1))) void*)g,
                                   (__attribute__((address_space(3))) void*)l, 16, 0, 0);
}

__global__ __launch_bounds__(256) void gemm_kernel(const f16* __restrict__ A,   // M_TOT x 768
                                                   const f16* __restrict__ Bt,  // 2304 x 768
                                                   const float* __restrict__ bq,
                                                   const float* __restrict__ bk,
                                                   const float* __restrict__ bv,
                                                   f16* __restrict__ C) {       // M_TOT x 2304
  constexpr int BM = 128, BK = 64;
  __shared__ __align__(16) f16 sA[BM * BK];   // 16 KB
  __shared__ __align__(16) f16 sB[BM * BK];   // 16 KB

  // XCD-bijective remap: grid 2592 = 8 XCDs * 324; XCD x gets bm in [18x, 18x+18), bn-fast.
  int orig = blockIdx.x;
  int wg = (orig & 7) * 324 + (orig >> 3);
  int bm = wg / 18, bn = wg % 18;
  int tid = threadIdx.x;
  int wave = tid >> 6, lane = tid & 63;
  int wm = (wave >> 1) * 64, wn = (wave & 1) * 64;
  int m0 = bm * BM, n0 = bn * BM;

  int srow = tid >> 3;                          // 0..31
  int gchunk = ((tid & 7) ^ (srow & 7) ^ (((srow >> 3) & 3) << 1)) * 8;

  f32x16 acc[2][2];
#pragma unroll
  for (int i = 0; i < 2; i++)
#pragma unroll
    for (int j = 0; j < 2; j++) acc[i][j] = 0.f;

  int r32 = lane & 31, q2 = lane >> 5;
  int fx = (r32 & 7) ^ (((r32 >> 3) & 3) << 1);

  for (int kk = 0; kk < ND; kk += BK) {
#pragma unroll
    for (int ps = 0; ps < 4; ps++) {
      async_copy16(A + (size_t)(m0 + ps * 32 + srow) * ND + kk + gchunk, sA + ps * 2048 + tid * 8);
      async_copy16(Bt + (size_t)(n0 + ps * 32 + srow) * ND + kk + gchunk, sB + ps * 2048 + tid * 8);
    }
    __syncthreads();

#pragma unroll
    for (int ks = 0; ks < 4; ks++) {
      f16x8 aF[2], bF[2];
#pragma unroll
      for (int mt = 0; mt < 2; mt++) {
        int R = wm + mt * 32 + r32;
        aF[mt] = *(const f16x8*)(sA + R * 64 + (((ks * 2 + q2) ^ fx) * 8));
      }
#pragma unroll
      for (int nt = 0; nt < 2; nt++) {
        int R = wn + nt * 32 + r32;
        bF[nt] = *(const f16x8*)(sB + R * 64 + (((ks * 2 + q2) ^ fx) * 8));
      }
#pragma unroll
      for (int mt = 0; mt < 2; mt++)
#pragma unroll
        for (int nt = 0; nt < 2; nt++)   // swapped operands -> C^T register layout
          acc[mt][nt] = __builtin_amdgcn_mfma_f32_32x32x16_f16(bF[nt], aF[mt], acc[mt][nt], 0, 0, 0);
    }
    __syncthreads();
  }

#pragma unroll
  for (int mt = 0; mt < 2; mt++) {
    int gm = m0 + wm + mt * 32 + r32;
#pragma unroll
    for (int nt = 0; nt < 2; nt++) {
#pragma unroll
      for (int g = 0; g < 4; g++) {
        int gn0 = n0 + wn + nt * 32 + 8 * g + 4 * q2;
        const float* bp = (gn0 < ND) ? (bq + gn0)
                        : ((gn0 < 2 * ND) ? (bk + gn0 - ND) : (bv + gn0 - 2 * ND));
        float4 bias = *(const float4*)bp;
        f16x4 o;
        o[0] = (f16)(acc[mt][nt][4 * g + 0] + bias.x);
        o[1] = (f16)(acc[mt][nt][4 * g + 1] + bias.y);
        o[2] = (f16)(acc[mt][nt][4 * g + 2] + bias.z);
        o[3] = (f16)(acc[mt][nt][4 * g + 3] + bias.w);
        *(f16x4*)(C + (size_t)gm * N_TOT + gn0) = o;
      }
    }
  }
}

// ---------------- kernel 4: bilinear sample + score + sigmoid*value; XCD-swizzled ------------
// f16x8 (16B) loads in a 1.5-pass layout: pass0 = all 64 lanes cover ch [0,512) at d=t*8;
// pass1 = lanes t<32 cover [512,768). 27 narrow 8B loads/wave -> 13.5 wide 16B loads, each
// wave transaction 1 KB. Same math, same coalescing, 16B-aligned.
__global__ __launch_bounds__(256) void sample_kernel(const f16* __restrict__ qkv,
                                                     const float* __restrict__ coords,
                                                     float* __restrict__ out) {
  int wave = threadIdx.x >> 6, t = threadIdx.x & 63;
  int x8 = blockIdx.x & 7;           // XCD heuristic (blockIdx % 8)
  int i = blockIdx.x >> 3;           // 0..575
  int b = x8 * 4 + (i / 144);        // batch
  int p = (i % 144) * 4 + wave;      // point in batch

  float gx = coords[(size_t)b * (2 * NS) + p * 2 + 0];
  float gy = coords[(size_t)b * (2 * NS) + p * 2 + 1];
  float ix = ((gx + 1.f) * (float)NG - 1.f) * 0.5f;
  float iy = ((gy + 1.f) * (float)NG - 1.f) * 0.5f;
  float x0f = floorf(ix), y0f = floorf(iy);
  float wx1 = ix - x0f, wx0 = 1.f - wx1;
  float wy1 = iy - y0f, wy0 = 1.f - wy1;
  int x0 = (int)x0f, y0 = (int)y0f, x1 = x0 + 1, y1 = y0 + 1;
  bool vx0 = (x0 >= 0) & (x0 <= NG - 1), vx1 = (x1 >= 0) & (x1 <= NG - 1);
  bool vy0 = (y0 >= 0) & (y0 <= NG - 1), vy1 = (y1 >= 0) & (y1 <= NG - 1);
  int cx0 = min(max(x0, 0), NG - 1), cx1 = min(max(x1, 0), NG - 1);
  int cy0 = min(max(y0, 0), NG - 1), cy1 = min(max(y1, 0), NG - 1);
  float w00 = wx0 * wy0 * ((vx0 && vy0) ? 1.f : 0.f);
  float w10 = wx1 * wy0 * ((vx1 && vy0) ? 1.f : 0.f);
  float w01 = wx0 * wy1 * ((vx0 && vy1) ? 1.f : 0.f);
  float w11 = wx1 * wy1 * ((vx1 && vy1) ? 1.f : 0.f);

  size_t base = (size_t)b * NS;
  const f16* r00 = qkv + (base + cy0 * NG + cx0) * N_TOT;
  const f16* r10 = qkv + (base + cy0 * NG + cx1) * N_TOT;
  const f16* r01 = qkv + (base + cy1 * NG + cx0) * N_TOT;
  const f16* r11 = qkv + (base + cy1 * NG + cx1) * N_TOT;
  const f16* qr  = qkv + (base + p) * N_TOT;

  float partial = 0.f;
  float sv0[8], sv1[8];
  bool act = (t < 32);

  // ---- pass 0: channels [0,512), all lanes, d = t*8 ----
  {
    int d = t * 8;
    f16x8 k00 = *(const f16x8*)(r00 + ND + d);
    f16x8 k10 = *(const f16x8*)(r10 + ND + d);
    f16x8 k01 = *(const f16x8*)(r01 + ND + d);
    f16x8 k11 = *(const f16x8*)(r11 + ND + d);
    f16x8 v00 = *(const f16x8*)(r00 + 2 * ND + d);
    f16x8 v10 = *(const f16x8*)(r10 + 2 * ND + d);
    f16x8 v01 = *(const f16x8*)(r01 + 2 * ND + d);
    f16x8 v11 = *(const f16x8*)(r11 + 2 * ND + d);
    f16x8 qv  = *(const f16x8*)(qr + d);
#pragma unroll
    for (int j = 0; j < 8; j++) {
      float sk = w00 * (float)k00[j] + w10 * (float)k10[j]
               + w01 * (float)k01[j] + w11 * (float)k11[j];
      float sv = w00 * (float)v00[j] + w10 * (float)v10[j]
               + w01 * (float)v01[j] + w11 * (float)v11[j];
      partial = fmaf((float)qv[j], sk, partial);
      sv0[j] = sv;
    }
  }
  // ---- pass 1: channels [512,768), lanes t<32, d = 512 + t*8 ----
  if (act) {
    int d = 512 + t * 8;
    f16x8 k00 = *(const f16x8*)(r00 + ND + d);
    f16x8 k10 = *(const f16x8*)(r10 + ND + d);
    f16x8 k01 = *(const f16x8*)(r01 + ND + d);
    f16x8 k11 = *(const f16x8*)(r11 + ND + d);
    f16x8 v00 = *(const f16x8*)(r00 + 2 * ND + d);
    f16x8 v10 = *(const f16x8*)(r10 + 2 * ND + d);
    f16x8 v01 = *(const f16x8*)(r01 + 2 * ND + d);
    f16x8 v11 = *(const f16x8*)(r11 + 2 * ND + d);
    f16x8 qv  = *(const f16x8*)(qr + d);
#pragma unroll
    for (int j = 0; j < 8; j++) {
      float sk = w00 * (float)k00[j] + w10 * (float)k10[j]
               + w01 * (float)k01[j] + w11 * (float)k11[j];
      float sv = w00 * (float)v00[j] + w10 * (float)v10[j]
               + w01 * (float)v01[j] + w11 * (float)v11[j];
      partial = fmaf((float)qv[j], sk, partial);
      sv1[j] = sv;
    }
  }

#pragma unroll
  for (int o = 32; o > 0; o >>= 1) partial += __shfl_down(partial, o);
  float score = __shfl(partial, 0);
  float sig = 1.f / (1.f + expf(-0.01f * score));
  float* orow = out + (size_t)(base + p) * ND;
  {
    int d = t * 8;
    float4 s0, s1;
    s0.x = sig * sv0[0]; s0.y = sig * sv0[1]; s0.z = sig * sv0[2]; s0.w = sig * sv0[3];
    s1.x = sig * sv0[4]; s1.y = sig * sv0[5]; s1.z = sig * sv0[6]; s1.w = sig * sv0[7];
    *(float4*)(orow + d) = s0;
    *(float4*)(orow + d + 4) = s1;
  }
  if (act) {
    int d = 512 + t * 8;
    float4 s0, s1;
    s0.x = sig * sv1[0]; s0.y = sig * sv1[1]; s0.z = sig * sv1[2]; s0.w = sig * sv1[3];
    s1.x = sig * sv1[4]; s1.y = sig * sv1[5]; s1.z = sig * sv1[6]; s1.w = sig * sv1[7];
    *(float4*)(orow + d) = s0;
    *(float4*)(orow + d + 4) = s1;
  }
}

extern "C" void kernel_launch(void* const* d_in, const int* in_sizes, int n_in,
                              void* d_out, int out_size, void* d_ws, size_t ws_size,
                              hipStream_t stream) {
  const float* x  = (const float*)d_in[0];
  const float* Wq = (const float*)d_in[2];
  const float* bq = (const float*)d_in[3];
  const float* Wk = (const float*)d_in[4];
  const float* bk = (const float*)d_in[5];
  const float* Wv = (const float*)d_in[6];
  const float* bv = (const float*)d_in[7];
  const float* W1 = (const float*)d_in[8];
  const float* b1 = (const float*)d_in[9];
  const float* W2 = (const float*)d_in[10];
  const float* b2 = (const float*)d_in[11];
  const float* W3 = (const float*)d_in[12];
  const float* b3 = (const float*)d_in[13];
  float* out = (float*)d_out;

  char* ws = (char*)d_ws;
  f16*   xb     = (f16*)(ws);                       // 28,311,552
  f16*   WT     = (f16*)(ws + 28311552);            //  3,538,944
  f16*   qkv    = (f16*)(ws + 31850496);            // 84,934,656
  // pre-gemm scratch carved from qkv region (consumed by z1 BEFORE gemm writes qkv):
  f16*   WcT_hi = (f16*)(ws + 31850496);            //     98,304
  f16*   WcT_lo = (f16*)(ws + 31948800);            //     98,304
  float* bc     = (float*)(ws + 116969472);         //        256
  float* coords = (float*)(ws + 121393408);         //    147,456 (total 121,540,864)

  prep_kernel<<<dim3(432 + 769), dim3(256), 0, stream>>>(Wq, Wk, Wv, bq, bk, W1, b1,
                                                         WT, WcT_hi, WcT_lo, bc);
  z1_fused_kernel<<<dim3(M_TOT / 16), dim3(256), 0, stream>>>(x, WcT_hi, WcT_lo, bc,
                                                              W2, b2, W3, b3, xb, coords);
  gemm_kernel<<<dim3((M_TOT / 128) * (N_TOT / 128)), dim3(256), 0, stream>>>(xb, WT, bq, bk, bv, qkv);
  sample_kernel<<<dim3(M_TOT / 4), dim3(256), 0, stream>>>(qkv, coords, out);
  (void)in_sizes; (void)n_in; (void)out_size; (void)ws_size;
}